// Round 4
// baseline (686.171 us; speedup 1.0000x reference)
//
#include <hip/hip_runtime.h>
#include <stdint.h>

// CMAALayer fused kernel, MI355X gfx950. Round 7.
// R6 post-mortem: 2 barrier domains regressed (2x weight traffic). R4=R5
// showed wave count is not the limit. Model: each barrier-phase uses ONE
// resource class (HBM / L2-weights+MFMA / LDS+VALU / LDS+HBM), phases sum
// serially to ~82 kcyc/block. Fix = make phases mix pipes:
//   - Persistent blocks: grid=256 (1/CU), 8 tiles each, software-pipelined.
//     Next tile's X global-loaded to regs during attention (HBM under VALU),
//     cvt+LDS-written during LN (VALU+ds_write under LDS-read/HBM-write).
//   - Swapped-operand MFMA (mfma(Wfrag, Xfrag)): C row=out-col, col=token ->
//     lane's 4 acc vals = 4 consecutive out-cols of one token row:
//     QKVR epilogue 16x ds_write_b64 (was 64x ds_write_b16), sY epilogue
//     4x ds_write_b128 + 4x ds_read_b64 (was 16x scalar r/w).
//   - Keeps R5 wins: fused sigmoid (1x/elem), single-pass attention,
//     barrier-free AO-over-Q overwrite, reg Wo frags, weight k-rotation.
// Geometry: RT=64, 1024 thr, 16 waves, LDS 130 KB, 5 barriers/tile.

#define D_DIM   256
#define H_NUM   8
#define DH      32
#define RT      64
#define NTHR    1024
#define NBLK    256
#define TPB     8                 // tiles per persistent block
#define ROWS_TOT 131072
#define Y_SZ    33554432          // 131072*256
#define SCALE_F 0.17677669529663687f
#define W_ELEMS 65536             // 256*256 per matrix
#define WS_NEED (5 * W_ELEMS * 2) // bytes for bf16 weight copy

#define SX_LD   264   // shorts
#define SQK_LD  776   // shorts per row: [Q/AO 0..255 | K 256..511 | Veff 512..767 | pad]
#define KOFF    256
#define VOFF    512
#define SY_LD   260   // floats (aliases sQK storage)

typedef __attribute__((ext_vector_type(8))) short bf16x8;
typedef __attribute__((ext_vector_type(4))) float f32x4;

__device__ __forceinline__ float b2f(uint16_t s) {
    union { uint32_t u; float f; } c; c.u = ((uint32_t)s) << 16; return c.f;
}
__device__ __forceinline__ uint16_t f2b(float f) {
    union { float f; uint32_t u; } c; c.f = f;
    return (uint16_t)((c.u + 0x7fffu + ((c.u >> 16) & 1u)) >> 16);
}
__device__ __forceinline__ bf16x8 cvt8(const float* p) {
    const float4 a = *(const float4*)p;
    const float4 b = *(const float4*)(p + 4);
    bf16x8 r;
    r[0] = (short)f2b(a.x); r[1] = (short)f2b(a.y);
    r[2] = (short)f2b(a.z); r[3] = (short)f2b(a.w);
    r[4] = (short)f2b(b.x); r[5] = (short)f2b(b.y);
    r[6] = (short)f2b(b.z); r[7] = (short)f2b(b.w);
    return r;
}
__device__ __forceinline__ uint2 pack4(f32x4 a) {
    uint2 p;
    p.x = (uint32_t)f2b(a[0]) | ((uint32_t)f2b(a[1]) << 16);
    p.y = (uint32_t)f2b(a[2]) | ((uint32_t)f2b(a[3]) << 16);
    return p;
}

// ---------------- K0: weight fp32 -> bf16 conversion ----------------
__global__ __launch_bounds__(256)
void conv_weights(const float* __restrict__ Wq, const float* __restrict__ Wk,
                  const float* __restrict__ Wv, const float* __restrict__ Wr,
                  const float* __restrict__ Wo, uint16_t* __restrict__ dst)
{
    const int m = blockIdx.x >> 6;                 // matrix id 0..4
    const float* src = (m == 0) ? Wq : (m == 1) ? Wk : (m == 2) ? Wv
                     : (m == 3) ? Wr : Wo;
    const int base = (blockIdx.x & 63) * 1024 + threadIdx.x * 4;
    const float4 v = *(const float4*)&src[base];
    uint2 pk;
    pk.x = (uint32_t)f2b(v.x) | ((uint32_t)f2b(v.y) << 16);
    pk.y = (uint32_t)f2b(v.z) | ((uint32_t)f2b(v.w) << 16);
    *(uint2*)&dst[(size_t)m * W_ELEMS + base] = pk;
}

// ---------------- K1: fused layer (persistent, pipelined) ----------------
template<bool WBF16>
__global__ __launch_bounds__(NTHR, 4)
void cmaa_fused(const float* __restrict__ tok,
                const float* __restrict__ Wq, const float* __restrict__ Wk,
                const float* __restrict__ Wv, const float* __restrict__ Wr,
                const float* __restrict__ Wo,
                const uint16_t* __restrict__ wbf,
                const float* __restrict__ lng, const float* __restrict__ lnb,
                float* __restrict__ outp)
{
    __shared__ __align__(16) uint16_t sX [RT * SX_LD];    // 33792 B
    __shared__ __align__(16) uint16_t sQK[RT * SQK_LD];   // 99328 B; also sY fp32

    const int tid  = threadIdx.x;
    const int wv   = tid >> 6;        // wave 0..15
    const int lane = tid & 63;
    const int l15  = lane & 15;
    const int quad = lane >> 4;
    const int koff = blockIdx.x & 7;  // weight k-stream rotation

    // wave roles for QKVR
    const bool qk      = (wv < 8);
    const int  colbase = (((wv & 7) + blockIdx.x) & 7) * 32;   // rotated col slice
    const int  wob     = ((wv + blockIdx.x) & 15) * 16;        // Wo col slice

    const float*    WF0 = qk ? Wq : Wv;
    const float*    WF1 = qk ? Wk : Wr;
    const uint16_t* WB0 = wbf + (size_t)(qk ? 0 : 2) * W_ELEMS;
    const uint16_t* WB1 = WB0 + W_ELEMS;
    const uint16_t* WoB = wbf + (size_t)4 * W_ELEMS;

    // stage-X thread mapping (2 iters x 8 elems)
    const int sx_r0 = tid >> 5;             const int sx_c0 = tid & 31;
    const int sx_r1 = (tid + 1024) >> 5;    const int sx_c1 = (tid + 1024) & 31;

    // ---------------- prologue: X(tile0) -> LDS ----------------
    const int tile0 = blockIdx.x * TPB;
    {
        const float* g = tok + (size_t)tile0 * RT * D_DIM;
        *(bf16x8*)&sX[sx_r0 * SX_LD + sx_c0 * 8] = cvt8(&g[sx_r0 * D_DIM + sx_c0 * 8]);
        *(bf16x8*)&sX[sx_r1 * SX_LD + sx_c1 * 8] = cvt8(&g[sx_r1 * D_DIM + sx_c1 * 8]);
    }
    __syncthreads();

    for (int t = 0; t < TPB; ++t) {
        const int R0 = (tile0 + t) * RT;

        // ---------------- QKVR GEMM (swapped operands) ----------------
        // waves 0..7: Q,K; waves 8..15: V,R. acc[mat][ct][nt]:
        //   out-col = colbase + ct*16 + quad*4 + r, token = nt*16 + l15
        {
            f32x4 acc[2][2][4];
            #pragma unroll
            for (int m = 0; m < 2; ++m)
                #pragma unroll
                for (int ct = 0; ct < 2; ++ct)
                    #pragma unroll
                    for (int nt = 0; nt < 4; ++nt)
                        acc[m][ct][nt] = (f32x4){0.f, 0.f, 0.f, 0.f};

            #pragma unroll
            for (int i = 0; i < 8; ++i) {
                const int k0 = ((i + koff) & 7) * 32;
                bf16x8 ax[4];
                #pragma unroll
                for (int nt = 0; nt < 4; ++nt)
                    ax[nt] = *(const bf16x8*)&sX[(nt * 16 + l15) * SX_LD + k0 + quad * 8];

                bf16x8 b0[2], b1[2];
                #pragma unroll
                for (int ct = 0; ct < 2; ++ct) {
                    const int wrow = colbase + ct * 16 + l15;
                    if constexpr (WBF16) {
                        b0[ct] = *(const bf16x8*)&WB0[(size_t)wrow * D_DIM + k0 + quad * 8];
                        b1[ct] = *(const bf16x8*)&WB1[(size_t)wrow * D_DIM + k0 + quad * 8];
                    } else {
                        b0[ct] = cvt8(&WF0[(size_t)wrow * D_DIM + k0 + quad * 8]);
                        b1[ct] = cvt8(&WF1[(size_t)wrow * D_DIM + k0 + quad * 8]);
                    }
                }
                #pragma unroll
                for (int ct = 0; ct < 2; ++ct)
                    #pragma unroll
                    for (int nt = 0; nt < 4; ++nt)
                        acc[0][ct][nt] = __builtin_amdgcn_mfma_f32_16x16x32_bf16(b0[ct], ax[nt], acc[0][ct][nt], 0, 0, 0);
                #pragma unroll
                for (int ct = 0; ct < 2; ++ct)
                    #pragma unroll
                    for (int nt = 0; nt < 4; ++nt)
                        acc[1][ct][nt] = __builtin_amdgcn_mfma_f32_16x16x32_bf16(b1[ct], ax[nt], acc[1][ct][nt], 0, 0, 0);
            }

            // packed epilogue: 4 consecutive out-cols per lane -> ds_write_b64
            if (qk) {
                #pragma unroll
                for (int ct = 0; ct < 2; ++ct)
                    #pragma unroll
                    for (int nt = 0; nt < 4; ++nt) {
                        const int token = nt * 16 + l15;
                        const int cb    = colbase + ct * 16 + quad * 4;
                        *(uint2*)&sQK[token * SQK_LD + cb]        = pack4(acc[0][ct][nt]);  // Q
                        *(uint2*)&sQK[token * SQK_LD + KOFF + cb] = pack4(acc[1][ct][nt]);  // K
                    }
            } else {
                #pragma unroll
                for (int ct = 0; ct < 2; ++ct)
                    #pragma unroll
                    for (int nt = 0; nt < 4; ++nt) {
                        const int token = nt * 16 + l15;
                        const int cb    = colbase + ct * 16 + quad * 4;
                        f32x4 ve;
                        #pragma unroll
                        for (int r = 0; r < 4; ++r) {
                            const float sig = 1.f / (1.f + __expf(-acc[1][ct][nt][r]));
                            ve[r] = acc[0][ct][nt][r] * sig;
                        }
                        *(uint2*)&sQK[token * SQK_LD + VOFF + cb] = pack4(ve);              // V_eff
                    }
            }
        }
        __syncthreads();

        // ---------------- prefetch: next X tile -> regs, Wo frags -> regs ----
        float4 xr0a, xr0b, xr1a, xr1b;
        if (t + 1 < TPB) {
            const float* gn = tok + (size_t)(R0 + RT) * D_DIM;
            xr0a = *(const float4*)&gn[sx_r0 * D_DIM + sx_c0 * 8];
            xr0b = *(const float4*)&gn[sx_r0 * D_DIM + sx_c0 * 8 + 4];
            xr1a = *(const float4*)&gn[sx_r1 * D_DIM + sx_c1 * 8];
            xr1b = *(const float4*)&gn[sx_r1 * D_DIM + sx_c1 * 8 + 4];
        }
        bf16x8 bw3[8];
        {
            const int worow = wob + l15;
            #pragma unroll
            for (int i = 0; i < 8; ++i) {
                const int k0 = ((i + koff) & 7) * 32;
                if constexpr (WBF16)
                    bw3[i] = *(const bf16x8*)&WoB[(size_t)worow * D_DIM + k0 + quad * 8];
                else
                    bw3[i] = cvt8(&Wo[(size_t)worow * D_DIM + k0 + quad * 8]);
            }
        }

        // ---------------- attention: 1024 thr = 64 rows x 8 heads x 2 halves ----
        {
            const int r    = tid >> 4;
            const int h    = (tid >> 1) & 7;
            const int half = tid & 1;
            const int gr = R0 + r;
            const int i  = r & 3;
            const int rb = r & ~3;
            int rn[3];
            #pragma unroll
            for (int l = 0; l < 3; ++l) { const int jj = l + (l >= i); rn[l] = rb + jj; }
            const int qoff = h * DH + half * 16;

            float q[16];
            #pragma unroll
            for (int tt = 0; tt < 2; ++tt) {
                const bf16x8 v = *(const bf16x8*)&sQK[r * SQK_LD + qoff + tt * 8];
                #pragma unroll
                for (int j = 0; j < 8; ++j) q[tt * 8 + j] = b2f((uint16_t)v[j]);
            }

            float sc[3];
            #pragma unroll
            for (int l = 0; l < 3; ++l) {
                float s = 0.f;
                #pragma unroll
                for (int tt = 0; tt < 2; ++tt) {
                    const bf16x8 v = *(const bf16x8*)&sQK[rn[l] * SQK_LD + KOFF + qoff + tt * 8];
                    #pragma unroll
                    for (int j = 0; j < 8; ++j) s += q[tt * 8 + j] * b2f((uint16_t)v[j]);
                }
                s += __shfl_xor(s, 1);          // combine the two 16-dim halves
                sc[l] = s * SCALE_F;
            }
            const float mx = fmaxf(sc[0], fmaxf(sc[1], sc[2]));
            const float e0 = __expf(sc[0] - mx), e1 = __expf(sc[1] - mx), e2 = __expf(sc[2] - mx);
            const float inv = 1.f / (e0 + e1 + e2);
            const float al[3] = { e0 * inv, e1 * inv, e2 * inv };

            if (half == 0) {
                float* ap = outp + Y_SZ + ((size_t)gr * H_NUM + h) * 3;
                ap[0] = al[0]; ap[1] = al[1]; ap[2] = al[2];
            }

            // PV: each thread overwrites exactly the Q bytes it alone read
            #pragma unroll
            for (int tt = 0; tt < 2; ++tt) {
                float o[8] = {0.f,0.f,0.f,0.f,0.f,0.f,0.f,0.f};
                #pragma unroll
                for (int l = 0; l < 3; ++l) {
                    const bf16x8 vv = *(const bf16x8*)&sQK[rn[l] * SQK_LD + VOFF + qoff + tt * 8];
                    #pragma unroll
                    for (int j = 0; j < 8; ++j) o[j] += al[l] * b2f((uint16_t)vv[j]);
                }
                bf16x8 pk;
                #pragma unroll
                for (int j = 0; j < 8; ++j) pk[j] = (short)f2b(o[j]);
                *(bf16x8*)&sQK[r * SQK_LD + qoff + tt * 8] = pk;   // AO over dead Q
            }
        }
        __syncthreads();

        // ---------------- AO @ Wo^T (swapped operands, weights in regs) ------
        f32x4 acc3[4];
        #pragma unroll
        for (int nt = 0; nt < 4; ++nt) acc3[nt] = (f32x4){0.f, 0.f, 0.f, 0.f};

        #pragma unroll
        for (int i = 0; i < 8; ++i) {
            const int k0 = ((i + koff) & 7) * 32;
            bf16x8 ao[4];
            #pragma unroll
            for (int nt = 0; nt < 4; ++nt)
                ao[nt] = *(const bf16x8*)&sQK[(nt * 16 + l15) * SQK_LD + k0 + quad * 8];
            #pragma unroll
            for (int nt = 0; nt < 4; ++nt)
                acc3[nt] = __builtin_amdgcn_mfma_f32_16x16x32_bf16(bw3[i], ao[nt], acc3[nt], 0, 0, 0);
        }
        __syncthreads();   // all AO reads done before sY aliases sQK

        // sY + residual: lane's 4 consecutive out-cols of one token row
        {
            float* sY = (float*)sQK;
            #pragma unroll
            for (int nt = 0; nt < 4; ++nt) {
                const int token = nt * 16 + l15;
                const int c0    = wob + quad * 4;
                const ushort4 xv = *(const ushort4*)&sX[token * SX_LD + c0];
                float4 y4;
                y4.x = acc3[nt][0] + b2f(xv.x);
                y4.y = acc3[nt][1] + b2f(xv.y);
                y4.z = acc3[nt][2] + b2f(xv.z);
                y4.w = acc3[nt][3] + b2f(xv.w);
                *(float4*)&sY[token * SY_LD + c0] = y4;
            }
        }
        __syncthreads();

        // ---------------- LN + store y; stage X(t+1) into sX ----------------
        {
            const float* sY = (const float*)sQK;
            const int row = tid >> 4;   // 64 rows x 16 lanes
            const int sub = tid & 15;
            float vals[16];
            float s = 0.f;
            #pragma unroll
            for (int j = 0; j < 4; ++j) {
                const float4 v = *(const float4*)&sY[row * SY_LD + j * 64 + sub * 4];
                vals[j*4+0] = v.x; vals[j*4+1] = v.y; vals[j*4+2] = v.z; vals[j*4+3] = v.w;
                s += v.x + v.y + v.z + v.w;
            }
            s += __shfl_xor(s, 1); s += __shfl_xor(s, 2);
            s += __shfl_xor(s, 4); s += __shfl_xor(s, 8);
            const float mean = s * (1.f / 256.f);
            float s2 = 0.f;
            #pragma unroll
            for (int j = 0; j < 16; ++j) { const float d = vals[j] - mean; s2 += d * d; }
            s2 += __shfl_xor(s2, 1); s2 += __shfl_xor(s2, 2);
            s2 += __shfl_xor(s2, 4); s2 += __shfl_xor(s2, 8);
            const float var  = fmaxf(s2 * (1.f / 256.f), 0.f);
            const float rstd = rsqrtf(var + 1e-5f);

            float* orow = outp + (size_t)(R0 + row) * D_DIM;
            #pragma unroll
            for (int j = 0; j < 4; ++j) {
                const int col = j * 64 + sub * 4;
                const float4 g4 = *(const float4*)&lng[col];
                const float4 b4 = *(const float4*)&lnb[col];
                float4 o4;
                o4.x = (vals[j*4+0] - mean) * rstd * g4.x + b4.x;
                o4.y = (vals[j*4+1] - mean) * rstd * g4.y + b4.y;
                o4.z = (vals[j*4+2] - mean) * rstd * g4.z + b4.z;
                o4.w = (vals[j*4+3] - mean) * rstd * g4.w + b4.w;
                *(float4*)&orow[col] = o4;
            }
        }
        if (t + 1 < TPB) {
            // write prefetched X(t+1) (regs) -> sX; overlaps the LN phase
            bf16x8 p0, p1;
            p0[0]=(short)f2b(xr0a.x); p0[1]=(short)f2b(xr0a.y); p0[2]=(short)f2b(xr0a.z); p0[3]=(short)f2b(xr0a.w);
            p0[4]=(short)f2b(xr0b.x); p0[5]=(short)f2b(xr0b.y); p0[6]=(short)f2b(xr0b.z); p0[7]=(short)f2b(xr0b.w);
            p1[0]=(short)f2b(xr1a.x); p1[1]=(short)f2b(xr1a.y); p1[2]=(short)f2b(xr1a.z); p1[3]=(short)f2b(xr1a.w);
            p1[4]=(short)f2b(xr1b.x); p1[5]=(short)f2b(xr1b.y); p1[6]=(short)f2b(xr1b.z); p1[7]=(short)f2b(xr1b.w);
            *(bf16x8*)&sX[sx_r0 * SX_LD + sx_c0 * 8] = p0;
            *(bf16x8*)&sX[sx_r1 * SX_LD + sx_c1 * 8] = p1;
        }
        __syncthreads();
    }
}

extern "C" void kernel_launch(void* const* d_in, const int* in_sizes, int n_in,
                              void* d_out, int out_size, void* d_ws, size_t ws_size,
                              hipStream_t stream) {
    (void)in_sizes; (void)n_in; (void)out_size;
    const float* tok = (const float*)d_in[0];
    const float* Wq  = (const float*)d_in[1];
    const float* Wk  = (const float*)d_in[2];
    const float* Wv  = (const float*)d_in[3];
    const float* Wr  = (const float*)d_in[4];
    const float* Wo  = (const float*)d_in[5];
    const float* lng = (const float*)d_in[6];
    const float* lnb = (const float*)d_in[7];
    float* outp = (float*)d_out;
    uint16_t* wbf = (uint16_t*)d_ws;

    dim3 grid(NBLK), block(NTHR);
    if (ws_size >= (size_t)WS_NEED) {
        conv_weights<<<dim3(320), dim3(256), 0, stream>>>(Wq, Wk, Wv, Wr, Wo, wbf);
        cmaa_fused<true><<<grid, block, 0, stream>>>(
            tok, Wq, Wk, Wv, Wr, Wo, wbf, lng, lnb, outp);
    } else {
        cmaa_fused<false><<<grid, block, 0, stream>>>(
            tok, Wq, Wk, Wv, Wr, Wo, wbf, lng, lnb, outp);
    }
}

// Round 5
// 429.480 us; speedup vs baseline: 1.5977x; 1.5977x over previous
//
#include <hip/hip_runtime.h>
#include <stdint.h>

// CMAALayer fused kernel, MI355X gfx950. Round 8.
// R7 post-mortem: persistence broke weight-L2 reuse (FETCH 82MB -> 1.02GB).
// Lockstep relaunch (grid 2048) IS the weight-cache mechanism. R4=R5/R6/R7
// evidence: the untried lever is 2 blocks/CU at RT=64 (cross-block phase
// overlap, weight traffic unchanged). Enabled by keeping Q/K/V_eff in regs:
//   - Swapped-operand GEMM (verified R7): wave = head; lane holds proj
//     (out-dim colbase+ct*16+quad*4+r, token nt*16+l15). The 4-token attn
//     group = 4 adjacent lanes; neighbors j of i are exactly i^m, m=1..3
//     -> scores/PV via __shfl_xor, no Q/K/V LDS at all.
//   - Waves 0..3 (Q,K head p*4+wv): scores+softmax in-wave; alpha (bf16) to
//     4KB LDS + attn-prob global store. Waves 4..7 (V,R same head):
//     V_eff=sigmoid(R)*V in regs; after barrier, PV via shfl -> AO LDS.
//   - LN in regs: per-wave y partial sums via 5KB LDS exchange; y written
//     straight from regs. No sY buffer.
// LDS: sX 33.8K + sAO 33.8K + alpha 4K + partials 5K = 75K -> 2 blocks/CU,
// 512 thr, __launch_bounds__(512,4) caps regs at 128 (R5 fit 64+64 exactly).
// 2 passes (4 heads each) over the same staged X; 6 barriers/block.

#define D_DIM   256
#define H_NUM   8
#define RT      64
#define NTHR    512
#define ROWS_TOT 131072
#define Y_SZ    33554432          // 131072*256
#define SCALE_F 0.17677669529663687f
#define W_ELEMS 65536             // 256*256 per matrix
#define WS_NEED (5 * W_ELEMS * 2) // bytes for bf16 weight copy

#define SX_LD   264   // shorts; 528B row stride, 16B-aligned
#define AO_LD   264
#define SP_LD   20    // floats; 80B row stride, 16B-aligned, 2-way-bank only

typedef __attribute__((ext_vector_type(8))) short bf16x8;
typedef __attribute__((ext_vector_type(4))) float f32x4;

__device__ __forceinline__ float b2f(uint16_t s) {
    union { uint32_t u; float f; } c; c.u = ((uint32_t)s) << 16; return c.f;
}
__device__ __forceinline__ uint16_t f2b(float f) {
    union { float f; uint32_t u; } c; c.f = f;
    return (uint16_t)((c.u + 0x7fffu + ((c.u >> 16) & 1u)) >> 16);
}
__device__ __forceinline__ bf16x8 cvt8(const float* p) {
    const float4 a = *(const float4*)p;
    const float4 b = *(const float4*)(p + 4);
    bf16x8 r;
    r[0] = (short)f2b(a.x); r[1] = (short)f2b(a.y);
    r[2] = (short)f2b(a.z); r[3] = (short)f2b(a.w);
    r[4] = (short)f2b(b.x); r[5] = (short)f2b(b.y);
    r[6] = (short)f2b(b.z); r[7] = (short)f2b(b.w);
    return r;
}
__device__ __forceinline__ uint2 pack4(f32x4 a) {
    uint2 p;
    p.x = (uint32_t)f2b(a[0]) | ((uint32_t)f2b(a[1]) << 16);
    p.y = (uint32_t)f2b(a[2]) | ((uint32_t)f2b(a[3]) << 16);
    return p;
}

// ---------------- K0: weight fp32 -> bf16 conversion ----------------
__global__ __launch_bounds__(256)
void conv_weights(const float* __restrict__ Wq, const float* __restrict__ Wk,
                  const float* __restrict__ Wv, const float* __restrict__ Wr,
                  const float* __restrict__ Wo, uint16_t* __restrict__ dst)
{
    const int m = blockIdx.x >> 6;                 // matrix id 0..4
    const float* src = (m == 0) ? Wq : (m == 1) ? Wk : (m == 2) ? Wv
                     : (m == 3) ? Wr : Wo;
    const int base = (blockIdx.x & 63) * 1024 + threadIdx.x * 4;
    const float4 v = *(const float4*)&src[base];
    uint2 pk;
    pk.x = (uint32_t)f2b(v.x) | ((uint32_t)f2b(v.y) << 16);
    pk.y = (uint32_t)f2b(v.z) | ((uint32_t)f2b(v.w) << 16);
    *(uint2*)&dst[(size_t)m * W_ELEMS + base] = pk;
}

// ---------------- K1: fused layer ----------------
template<bool WBF16>
__global__ __launch_bounds__(NTHR, 4)
void cmaa_fused(const float* __restrict__ tok,
                const float* __restrict__ Wq, const float* __restrict__ Wk,
                const float* __restrict__ Wv, const float* __restrict__ Wr,
                const float* __restrict__ Wo,
                const uint16_t* __restrict__ wbf,
                const float* __restrict__ lng, const float* __restrict__ lnb,
                float* __restrict__ outp)
{
    __shared__ __align__(16) uint16_t sX [RT * SX_LD];    // 33792 B
    __shared__ __align__(16) uint16_t sAO[RT * AO_LD];    // 33792 B
    __shared__ __align__(16) uint16_t sAL[RT * H_NUM * 4];// 4096 B: alpha bf16 [tok][h][4]
    __shared__ __align__(16) float    sPT[RT * SP_LD];    // 5120 B: LN partials [tok][8w*2]

    const int tid  = threadIdx.x;
    const int wv   = tid >> 6;        // wave 0..7
    const int lane = tid & 63;
    const int l15  = lane & 15;
    const int quad = lane >> 4;
    const int R0   = blockIdx.x * RT;

    // ---------------- stage 0: X tile -> LDS (bf16) ----------------
    {
        const float* g = tok + (size_t)R0 * D_DIM;
        #pragma unroll
        for (int it = 0; it < 4; ++it) {
            const int t = tid + it * NTHR;
            const int row = t >> 5, c = t & 31;
            *(bf16x8*)&sX[row * SX_LD + c * 8] = cvt8(&g[row * D_DIM + c * 8]);
        }
    }
    __syncthreads();

    const bool qk = (wv < 4);
    const int  hl = wv & 3;

    #pragma unroll
    for (int p = 0; p < 2; ++p) {
        const int h = p * 4 + hl;          // this wave's head for this pass
        const int colbase = h * 32;
        const float*    WF0 = qk ? Wq : Wv;
        const float*    WF1 = qk ? Wk : Wr;
        const uint16_t* WB0 = wbf + (size_t)(qk ? 0 : 2) * W_ELEMS;
        const uint16_t* WB1 = WB0 + W_ELEMS;

        // ---------- projection GEMM: this head's 32 cols of 2 matrices ----
        // acc[m][ct][nt][r] = proj[out-dim colbase+ct*16+quad*4+r][token nt*16+l15]
        f32x4 acc[2][2][4];
        #pragma unroll
        for (int m = 0; m < 2; ++m)
            #pragma unroll
            for (int ct = 0; ct < 2; ++ct)
                #pragma unroll
                for (int nt = 0; nt < 4; ++nt)
                    acc[m][ct][nt] = (f32x4){0.f, 0.f, 0.f, 0.f};

        #pragma unroll
        for (int kk = 0; kk < 8; ++kk) {
            const int k0 = kk * 32;
            bf16x8 ax[4];
            #pragma unroll
            for (int nt = 0; nt < 4; ++nt)
                ax[nt] = *(const bf16x8*)&sX[(nt * 16 + l15) * SX_LD + k0 + quad * 8];
            bf16x8 b0[2], b1[2];
            #pragma unroll
            for (int ct = 0; ct < 2; ++ct) {
                const int wrow = colbase + ct * 16 + l15;
                if constexpr (WBF16) {
                    b0[ct] = *(const bf16x8*)&WB0[(size_t)wrow * D_DIM + k0 + quad * 8];
                    b1[ct] = *(const bf16x8*)&WB1[(size_t)wrow * D_DIM + k0 + quad * 8];
                } else {
                    b0[ct] = cvt8(&WF0[(size_t)wrow * D_DIM + k0 + quad * 8]);
                    b1[ct] = cvt8(&WF1[(size_t)wrow * D_DIM + k0 + quad * 8]);
                }
            }
            #pragma unroll
            for (int ct = 0; ct < 2; ++ct)
                #pragma unroll
                for (int nt = 0; nt < 4; ++nt)
                    acc[0][ct][nt] = __builtin_amdgcn_mfma_f32_16x16x32_bf16(b0[ct], ax[nt], acc[0][ct][nt], 0, 0, 0);
            #pragma unroll
            for (int ct = 0; ct < 2; ++ct)
                #pragma unroll
                for (int nt = 0; nt < 4; ++nt)
                    acc[1][ct][nt] = __builtin_amdgcn_mfma_f32_16x16x32_bf16(b1[ct], ax[nt], acc[1][ct][nt], 0, 0, 0);
        }

        if (qk) {
            // ---------- scores + softmax, fully in-wave ----------
            // neighbor j of token i is i^m (m=1..3); lanes of a 4-group are adjacent
            #pragma unroll
            for (int nt = 0; nt < 4; ++nt) {
                float sc[3];
                #pragma unroll
                for (int m = 1; m <= 3; ++m) {
                    float s = 0.f;
                    #pragma unroll
                    for (int ct = 0; ct < 2; ++ct)
                        #pragma unroll
                        for (int r = 0; r < 4; ++r)
                            s += acc[0][ct][nt][r] * __shfl_xor(acc[1][ct][nt][r], m);
                    s += __shfl_xor(s, 16);      // reduce over quads
                    s += __shfl_xor(s, 32);
                    sc[m - 1] = s * SCALE_F;
                }
                const float mx = fmaxf(sc[0], fmaxf(sc[1], sc[2]));
                const float e1 = __expf(sc[0] - mx), e2 = __expf(sc[1] - mx), e3 = __expf(sc[2] - mx);
                const float inv = 1.f / (e1 + e2 + e3);
                const float a1 = e1 * inv, a2 = e2 * inv, a3 = e3 * inv;
                const int token = nt * 16 + l15;
                if (quad == 0) {
                    ushort4 aw;
                    aw.x = 0; aw.y = f2b(a1); aw.z = f2b(a2); aw.w = f2b(a3);
                    *(ushort4*)&sAL[(token * H_NUM + h) * 4] = aw;
                    // attn probs (fp32) in reference l-order: jj = l + (l>=ii), m = ii^jj
                    const int ii = token & 3;
                    float* ap = outp + Y_SZ + ((size_t)(R0 + token) * H_NUM + h) * 3;
                    #pragma unroll
                    for (int l = 0; l < 3; ++l) {
                        const int jj = l + (l >= ii);
                        const int m  = ii ^ jj;
                        ap[l] = (m == 1) ? a1 : ((m == 2) ? a2 : a3);
                    }
                }
            }
        } else {
            // ---------- V_eff = sigmoid(R)*V in regs ----------
            #pragma unroll
            for (int ct = 0; ct < 2; ++ct)
                #pragma unroll
                for (int nt = 0; nt < 4; ++nt)
                    #pragma unroll
                    for (int r = 0; r < 4; ++r)
                        acc[0][ct][nt][r] *= 1.f / (1.f + __expf(-acc[1][ct][nt][r]));
        }
        __syncthreads();   // alphas visible to V-waves

        if (!qk) {
            // ---------- PV via shuffles -> AO to LDS ----------
            #pragma unroll
            for (int nt = 0; nt < 4; ++nt) {
                const int token = nt * 16 + l15;
                const ushort4 aw = *(const ushort4*)&sAL[(token * H_NUM + h) * 4];
                const float a1 = b2f(aw.y), a2 = b2f(aw.z), a3 = b2f(aw.w);
                #pragma unroll
                for (int ct = 0; ct < 2; ++ct) {
                    f32x4 ao;
                    #pragma unroll
                    for (int r = 0; r < 4; ++r) {
                        const float v = acc[0][ct][nt][r];
                        ao[r] = a1 * __shfl_xor(v, 1)
                              + a2 * __shfl_xor(v, 2)
                              + a3 * __shfl_xor(v, 3);
                    }
                    *(uint2*)&sAO[token * AO_LD + colbase + ct * 16 + quad * 4] = pack4(ao);
                }
            }
        }
        __syncthreads();   // pass done (AO writes of this pass complete)
    }

    // ---------------- AO @ Wo^T (swapped operands) ----------------
    const uint16_t* WoB = wbf + (size_t)4 * W_ELEMS;
    f32x4 acc3[2][4];   // [ct][nt]: out-col wv*32+ct*16+quad*4+r, token nt*16+l15
    #pragma unroll
    for (int ct = 0; ct < 2; ++ct)
        #pragma unroll
        for (int nt = 0; nt < 4; ++nt)
            acc3[ct][nt] = (f32x4){0.f, 0.f, 0.f, 0.f};

    #pragma unroll
    for (int kk = 0; kk < 8; ++kk) {
        const int k0 = kk * 32;
        bf16x8 ao[4];
        #pragma unroll
        for (int nt = 0; nt < 4; ++nt)
            ao[nt] = *(const bf16x8*)&sAO[(nt * 16 + l15) * AO_LD + k0 + quad * 8];
        bf16x8 bw[2];
        #pragma unroll
        for (int ct = 0; ct < 2; ++ct) {
            const int wrow = wv * 32 + ct * 16 + l15;
            if constexpr (WBF16)
                bw[ct] = *(const bf16x8*)&WoB[(size_t)wrow * D_DIM + k0 + quad * 8];
            else
                bw[ct] = cvt8(&Wo[(size_t)wrow * D_DIM + k0 + quad * 8]);
        }
        #pragma unroll
        for (int ct = 0; ct < 2; ++ct)
            #pragma unroll
            for (int nt = 0; nt < 4; ++nt)
                acc3[ct][nt] = __builtin_amdgcn_mfma_f32_16x16x32_bf16(bw[ct], ao[nt], acc3[ct][nt], 0, 0, 0);
    }

    // ---------------- residual + LN partials (in regs) ----------------
    #pragma unroll
    for (int nt = 0; nt < 4; ++nt) {
        const int token = nt * 16 + l15;
        float s1 = 0.f, s2 = 0.f;
        #pragma unroll
        for (int ct = 0; ct < 2; ++ct) {
            const ushort4 xv = *(const ushort4*)&sX[token * SX_LD + wv * 32 + ct * 16 + quad * 4];
            const float x0 = b2f(xv.x), x1 = b2f(xv.y), x2 = b2f(xv.z), x3 = b2f(xv.w);
            acc3[ct][nt][0] += x0; acc3[ct][nt][1] += x1;
            acc3[ct][nt][2] += x2; acc3[ct][nt][3] += x3;
            #pragma unroll
            for (int r = 0; r < 4; ++r) {
                const float y = acc3[ct][nt][r];
                s1 += y; s2 += y * y;
            }
        }
        s1 += __shfl_xor(s1, 16); s1 += __shfl_xor(s1, 32);
        s2 += __shfl_xor(s2, 16); s2 += __shfl_xor(s2, 32);
        if (quad == 0) {
            float2 ps; ps.x = s1; ps.y = s2;
            *(float2*)&sPT[token * SP_LD + wv * 2] = ps;
        }
    }
    __syncthreads();

    // ---------------- LN finalize + store y from regs ----------------
    #pragma unroll
    for (int nt = 0; nt < 4; ++nt) {
        const int token = nt * 16 + l15;
        const f32x4* pp = (const f32x4*)&sPT[token * SP_LD];
        const f32x4 q0 = pp[0], q1 = pp[1], q2 = pp[2], q3 = pp[3];
        const float s1 = q0[0] + q0[2] + q1[0] + q1[2] + q2[0] + q2[2] + q3[0] + q3[2];
        const float s2 = q0[1] + q0[3] + q1[1] + q1[3] + q2[1] + q2[3] + q3[1] + q3[3];
        const float mean = s1 * (1.f / 256.f);
        const float var  = fmaxf(s2 * (1.f / 256.f) - mean * mean, 0.f);
        const float rstd = rsqrtf(var + 1e-5f);
        float* orow = outp + (size_t)(R0 + token) * D_DIM;
        #pragma unroll
        for (int ct = 0; ct < 2; ++ct) {
            const int c0 = wv * 32 + ct * 16 + quad * 4;
            const float4 g4 = *(const float4*)&lng[c0];
            const float4 b4 = *(const float4*)&lnb[c0];
            float4 o4;
            o4.x = (acc3[ct][nt][0] - mean) * rstd * g4.x + b4.x;
            o4.y = (acc3[ct][nt][1] - mean) * rstd * g4.y + b4.y;
            o4.z = (acc3[ct][nt][2] - mean) * rstd * g4.z + b4.z;
            o4.w = (acc3[ct][nt][3] - mean) * rstd * g4.w + b4.w;
            *(float4*)&orow[c0] = o4;
        }
    }
}

extern "C" void kernel_launch(void* const* d_in, const int* in_sizes, int n_in,
                              void* d_out, int out_size, void* d_ws, size_t ws_size,
                              hipStream_t stream) {
    (void)in_sizes; (void)n_in; (void)out_size;
    const float* tok = (const float*)d_in[0];
    const float* Wq  = (const float*)d_in[1];
    const float* Wk  = (const float*)d_in[2];
    const float* Wv  = (const float*)d_in[3];
    const float* Wr  = (const float*)d_in[4];
    const float* Wo  = (const float*)d_in[5];
    const float* lng = (const float*)d_in[6];
    const float* lnb = (const float*)d_in[7];
    float* outp = (float*)d_out;
    uint16_t* wbf = (uint16_t*)d_ws;

    dim3 grid(ROWS_TOT / RT), block(NTHR);
    if (ws_size >= (size_t)WS_NEED) {
        conv_weights<<<dim3(320), dim3(256), 0, stream>>>(Wq, Wk, Wv, Wr, Wo, wbf);
        cmaa_fused<true><<<grid, block, 0, stream>>>(
            tok, Wq, Wk, Wv, Wr, Wo, wbf, lng, lnb, outp);
    } else {
        cmaa_fused<false><<<grid, block, 0, stream>>>(
            tok, Wq, Wk, Wv, Wr, Wo, wbf, lng, lnb, outp);
    }
}